// Round 2
// baseline (4085.203 us; speedup 1.0000x reference)
//
#include <hip/hip_runtime.h>
#include <hip/hip_bf16.h>

#define BATCH 64
#define SEQ 2048
#define IN_DIM 256
#define UNITS 256

typedef _Float16 half2_t __attribute__((ext_vector_type(2)));

__device__ __forceinline__ float fdot2(half2_t a, half2_t b, float c) {
#if __has_builtin(__builtin_amdgcn_fdot2)
    return __builtin_amdgcn_fdot2(a, b, c, false);
#else
    return c + (float)a[0] * (float)b[0] + (float)a[1] * (float)b[1];
#endif
}

// DPP butterfly add over the 16 lanes of a row (all lanes end with the sum).
template <int CTRL>
__device__ __forceinline__ float dpp_xor_add(float v) {
    int s = __builtin_amdgcn_update_dpp(0, __float_as_int(v), CTRL, 0xF, 0xF, true);
    return v + __int_as_float(s);
}
__device__ __forceinline__ float row16_sum(float v) {
    v = dpp_xor_add<0xB1>(v);    // quad_perm {1,0,3,2} : xor 1
    v = dpp_xor_add<0x4E>(v);    // quad_perm {2,3,0,1} : xor 2
    v = dpp_xor_add<0x141>(v);   // row_half_mirror    : xor 7 (completes 0..7)
    v = dpp_xor_add<0x140>(v);   // row_mirror         : xor 15
    return v;
}

// ---------------------------------------------------------------------------
// Prep: transpose U_f, U_s (K x U, fp32) -> Ut (U x K, f16).
// ---------------------------------------------------------------------------
__global__ void prep_u(const float* __restrict__ Uf, const float* __restrict__ Us,
                       _Float16* __restrict__ Utf, _Float16* __restrict__ Uts) {
    int idx = blockIdx.x * 256 + threadIdx.x;   // 65536 total
    int k = idx >> 8;
    int u = idx & 255;
    Utf[u * 256 + k] = (_Float16)Uf[idx];
    Uts[u * 256 + k] = (_Float16)Us[idx];
}

// ---------------------------------------------------------------------------
// Projection GEMM (unchanged this round): 64x64 tile, fp32.
// ---------------------------------------------------------------------------
__global__ __launch_bounds__(256) void proj_kernel(
    const float* __restrict__ X,
    const float* __restrict__ Wf, const float* __restrict__ bf,
    const float* __restrict__ Wsm, const float* __restrict__ bs,
    float* __restrict__ xf_out, _Float16* __restrict__ xs_out)
{
    __shared__ float Xs[64][65];
    __shared__ float Wsh[64][68];

    const int tid = threadIdx.x;
    const int rt = blockIdx.x;
    const int ct = blockIdx.y;
    const int r0 = rt * 64;
    const bool is_f = ct < 4;
    const int c0 = (ct & 3) * 64;
    const float* W = is_f ? Wf : Wsm;
    const float* bias = is_f ? bf : bs;
    const int tx = tid & 15;
    const int ty = tid >> 4;

    float acc[4][4];
#pragma unroll
    for (int i = 0; i < 4; ++i)
#pragma unroll
        for (int j = 0; j < 4; ++j) acc[i][j] = 0.f;

    for (int kc = 0; kc < IN_DIM; kc += 64) {
        __syncthreads();
#pragma unroll
        for (int i = 0; i < 4; ++i) {
            int f = tid + i * 256;
            int row = f >> 4;
            int kq = f & 15;
            float4 v = *(const float4*)(X + (size_t)(r0 + row) * IN_DIM + kc + kq * 4);
            Xs[row][kq * 4 + 0] = v.x;
            Xs[row][kq * 4 + 1] = v.y;
            Xs[row][kq * 4 + 2] = v.z;
            Xs[row][kq * 4 + 3] = v.w;
        }
#pragma unroll
        for (int i = 0; i < 4; ++i) {
            int f = tid + i * 256;
            int kk = f >> 4;
            int n4 = f & 15;
            float4 v = *(const float4*)(W + (size_t)(kc + kk) * UNITS + c0 + n4 * 4);
            *(float4*)&Wsh[kk][n4 * 4] = v;
        }
        __syncthreads();
#pragma unroll 8
        for (int kk = 0; kk < 64; ++kk) {
            float a0 = Xs[tx * 4 + 0][kk];
            float a1 = Xs[tx * 4 + 1][kk];
            float a2 = Xs[tx * 4 + 2][kk];
            float a3 = Xs[tx * 4 + 3][kk];
            float4 bv = *(const float4*)&Wsh[kk][ty * 4];
            acc[0][0] += a0 * bv.x; acc[0][1] += a0 * bv.y; acc[0][2] += a0 * bv.z; acc[0][3] += a0 * bv.w;
            acc[1][0] += a1 * bv.x; acc[1][1] += a1 * bv.y; acc[1][2] += a1 * bv.z; acc[1][3] += a1 * bv.w;
            acc[2][0] += a2 * bv.x; acc[2][1] += a2 * bv.y; acc[2][2] += a2 * bv.z; acc[2][3] += a2 * bv.w;
            acc[3][0] += a3 * bv.x; acc[3][1] += a3 * bv.y; acc[3][2] += a3 * bv.z; acc[3][3] += a3 * bv.w;
        }
    }

#pragma unroll
    for (int i = 0; i < 4; ++i) {
        int r = r0 + tx * 4 + i;
        int n0 = c0 + ty * 4;
        if (is_f) {
            float4 v;
            v.x = acc[i][0] + bias[n0 + 0];
            v.y = acc[i][1] + bias[n0 + 1];
            v.z = acc[i][2] + bias[n0 + 2];
            v.w = acc[i][3] + bias[n0 + 3];
            *(float4*)(xf_out + (size_t)r * UNITS + n0) = v;
        } else {
#pragma unroll
            for (int j = 0; j < 4; ++j)
                xs_out[(size_t)r * UNITS + n0 + j] = (_Float16)(acc[i][j] + bias[n0 + j]);
        }
    }
}

// ---------------------------------------------------------------------------
// Recurrence v2: one block (1024 thr) per batch.
// Thread (wave w, row r=lane>>4, col g=lane&15) covers outputs
// u = 16w + 4r + {0..3} over k-slice [16g, 16g+16).
//   - h/g vectors read from LDS: only 2 x ds_read_b128 per lane per phase
//     (4x less broadcast traffic than v1).
//   - k-partials reduced across the 16 g-lanes IN REGISTER via DPP butterfly.
//   - lane g==0 writes the 4 packed sums (one float4) to LDS.
//   - gate phases: 256 threads, h_old and f persist in registers (no LDS).
// LDS groups padded to 24 f16 (48 B) so the strided b128 reads are 2-way max.
// ---------------------------------------------------------------------------
__global__ __launch_bounds__(1024) void recur_kernel(
    float* xf_out,                       // aliases d_out: xf in, h out (no restrict!)
    const _Float16* __restrict__ xs16,   // [B][T][U]
    const _Float16* __restrict__ Utf,    // [U][K] f16
    const _Float16* __restrict__ Uts)    // [U][K] f16
{
    __shared__ __align__(16) _Float16 h2p[16 * 24];   // 16 groups x 16 (+8 pad)
    __shared__ __align__(16) _Float16 g2p[16 * 24];
    __shared__ float sumf[256];
    __shared__ float sums[256];

    const int tid = threadIdx.x;
    const int w = tid >> 6;
    const int lane = tid & 63;
    const int g = lane & 15;        // k-group: k in [16g, 16g+16)
    const int r = lane >> 4;        // u-sub
    const int u0 = 16 * w + 4 * r;  // first of 4 outputs
    const int b = blockIdx.x;

    union F4H { float4 f4; half2_t h[4]; };

    // Register-resident weights: U[16g+2j(+1)][u0+i] pairs.
    half2_t uf[4][8], us[4][8];
#pragma unroll
    for (int i = 0; i < 4; ++i) {
        const float4* pf = (const float4*)(Utf + ((size_t)(u0 + i) * 256 + 16 * g));
        const float4* ps = (const float4*)(Uts + ((size_t)(u0 + i) * 256 + 16 * g));
        F4H a0; a0.f4 = pf[0];
        F4H a1; a1.f4 = pf[1];
        F4H c0; c0.f4 = ps[0];
        F4H c1; c1.f4 = ps[1];
#pragma unroll
        for (int m = 0; m < 4; ++m) {
            uf[i][m] = a0.h[m];
            uf[i][4 + m] = a1.h[m];
            us[i][m] = c0.h[m];
            us[i][4 + m] = c1.h[m];
        }
    }

    if (tid < 16 * 24) h2p[tid] = (_Float16)0.f;

    const size_t base = (size_t)b * SEQ * UNITS;

    // Gate-thread state (tid < 256): unit u = tid.
    float h_old = 0.f, f_gate = 0.f;
    float xf_cur = 0.f, xs_cur = 0.f;
    if (tid < 256) {
        xf_cur = xf_out[base + tid];
        xs_cur = (float)xs16[base + tid];
    }
    __syncthreads();

    for (int t = 0; t < SEQ; ++t) {
        const int tn = (t + 1 < SEQ) ? t + 1 : t;

        // ---- phase a: partials of h @ U_f  (DPP-reduced across g-lanes)
        {
            const float4* hv4 = (const float4*)(h2p + g * 24);
            F4H h0; h0.f4 = hv4[0];
            F4H h1; h1.f4 = hv4[1];
            float a0 = 0.f, a1 = 0.f, a2 = 0.f, a3 = 0.f;
#pragma unroll
            for (int m = 0; m < 4; ++m) {
                a0 = fdot2(uf[0][m], h0.h[m], a0);
                a1 = fdot2(uf[1][m], h0.h[m], a1);
                a2 = fdot2(uf[2][m], h0.h[m], a2);
                a3 = fdot2(uf[3][m], h0.h[m], a3);
            }
#pragma unroll
            for (int m = 0; m < 4; ++m) {
                a0 = fdot2(uf[0][4 + m], h1.h[m], a0);
                a1 = fdot2(uf[1][4 + m], h1.h[m], a1);
                a2 = fdot2(uf[2][4 + m], h1.h[m], a2);
                a3 = fdot2(uf[3][4 + m], h1.h[m], a3);
            }
            a0 = row16_sum(a0); a1 = row16_sum(a1);
            a2 = row16_sum(a2); a3 = row16_sum(a3);
            if (g == 0) {
                float4 v; v.x = a0; v.y = a1; v.z = a2; v.w = a3;
                *(float4*)(sumf + u0) = v;
            }
        }
        __syncthreads();

        // ---- phase b: forget gate (256 threads, state in registers)
        float xf_nxt = 0.f;
        if (tid < 256) {
            float f = 1.f / (1.f + __expf(-(xf_cur + sumf[tid])));
            f_gate = f;
            g2p[(tid >> 4) * 24 + (tid & 15)] = (_Float16)(f * h_old);
            xf_nxt = xf_out[base + (size_t)tn * UNITS + tid];
        }
        __syncthreads();

        // ---- phase c: partials of (f*h) @ U_s
        {
            const float4* gv4 = (const float4*)(g2p + g * 24);
            F4H h0; h0.f4 = gv4[0];
            F4H h1; h1.f4 = gv4[1];
            float a0 = 0.f, a1 = 0.f, a2 = 0.f, a3 = 0.f;
#pragma unroll
            for (int m = 0; m < 4; ++m) {
                a0 = fdot2(us[0][m], h0.h[m], a0);
                a1 = fdot2(us[1][m], h0.h[m], a1);
                a2 = fdot2(us[2][m], h0.h[m], a2);
                a3 = fdot2(us[3][m], h0.h[m], a3);
            }
#pragma unroll
            for (int m = 0; m < 4; ++m) {
                a0 = fdot2(us[0][4 + m], h1.h[m], a0);
                a1 = fdot2(us[1][4 + m], h1.h[m], a1);
                a2 = fdot2(us[2][4 + m], h1.h[m], a2);
                a3 = fdot2(us[3][4 + m], h1.h[m], a3);
            }
            a0 = row16_sum(a0); a1 = row16_sum(a1);
            a2 = row16_sum(a2); a3 = row16_sum(a3);
            if (g == 0) {
                float4 v; v.x = a0; v.y = a1; v.z = a2; v.w = a3;
                *(float4*)(sums + u0) = v;
            }
        }
        __syncthreads();

        // ---- phase d: candidate + state update + output
        if (tid < 256) {
            float z = xs_cur + sums[tid];
            z = fminf(fmaxf(z, -15.f), 15.f);
            float e = __expf(2.f * z);
            float s = (e - 1.f) / (e + 1.f);
            float hn = (1.f - f_gate) * h_old + f_gate * s;
            h_old = hn;
            h2p[(tid >> 4) * 24 + (tid & 15)] = (_Float16)hn;
            xf_out[base + (size_t)t * UNITS + tid] = hn;
            xf_cur = xf_nxt;
            xs_cur = (float)xs16[base + (size_t)tn * UNITS + tid];
        }
        __syncthreads();
    }
}

extern "C" void kernel_launch(void* const* d_in, const int* in_sizes, int n_in,
                              void* d_out, int out_size, void* d_ws, size_t ws_size,
                              hipStream_t stream) {
    (void)in_sizes; (void)n_in; (void)out_size; (void)ws_size;

    const float* X   = (const float*)d_in[0];
    const float* Wf  = (const float*)d_in[1];
    const float* Uf  = (const float*)d_in[2];
    const float* bf  = (const float*)d_in[3];
    const float* Wsm = (const float*)d_in[4];
    const float* Us  = (const float*)d_in[5];
    const float* bs  = (const float*)d_in[6];
    float* out = (float*)d_out;

    // ws layout: xs16 (64 MB) | Utf (128 KB) | Uts (128 KB)
    _Float16* xs16 = (_Float16*)d_ws;
    _Float16* Utf  = xs16 + (size_t)BATCH * SEQ * UNITS;
    _Float16* Uts  = Utf + 256 * 256;

    prep_u<<<256, 256, 0, stream>>>(Uf, Us, Utf, Uts);
    proj_kernel<<<dim3(BATCH * SEQ / 64, 8), 256, 0, stream>>>(X, Wf, bf, Wsm, bs, out, xs16);
    recur_kernel<<<BATCH, 1024, 0, stream>>>(out, xs16, Utf, Uts);
}